// Round 6
// baseline (166.585 us; speedup 1.0000x reference)
//
#include <hip/hip_runtime.h>

typedef short short8 __attribute__((ext_vector_type(8)));
typedef unsigned short ushort8 __attribute__((ext_vector_type(8)));
typedef float f32x4 __attribute__((ext_vector_type(4)));

__device__ __forceinline__ unsigned short f32_to_bf16(float f) {
  unsigned u = __float_as_uint(f);
  unsigned r = 0x7fffu + ((u >> 16) & 1u);
  return (unsigned short)((u + r) >> 16);
}
__device__ __forceinline__ float bf16_to_f32(unsigned short h) {
  return __uint_as_float(((unsigned)h) << 16);
}

// ---------------- f32 -> bf16 convert (vectorized, 8 elems/thread) ----------
__global__ void cvt_f32_bf16(const float* __restrict__ s,
                             unsigned short* __restrict__ d, int n8) {
  int i = blockIdx.x * blockDim.x + threadIdx.x;
  if (i >= n8) return;
  const float4* sp = (const float4*)s;
  float4 a = sp[2 * i], b = sp[2 * i + 1];
  ushort8 o;
  o[0] = f32_to_bf16(a.x); o[1] = f32_to_bf16(a.y);
  o[2] = f32_to_bf16(a.z); o[3] = f32_to_bf16(a.w);
  o[4] = f32_to_bf16(b.x); o[5] = f32_to_bf16(b.y);
  o[6] = f32_to_bf16(b.z); o[7] = f32_to_bf16(b.w);
  ((ushort8*)d)[i] = o;
}

// ---------------- async global->LDS (16B/lane, wave-uniform LDS base) -------
__device__ __forceinline__ void gload_lds16(const void* g, void* l) {
  auto* gp = (const __attribute__((address_space(1))) uint32_t*)((uintptr_t)g);
  auto* lp = (__attribute__((address_space(3))) uint32_t*)(uint32_t)(uintptr_t)l;
  __builtin_amdgcn_global_load_lds(gp, lp, 16, 0, 0);
}

// ---------------- 16-point DFT (radix 4x4, constant twiddles) ---------------
constexpr float C16T[16] = {
    1.f,  0.9238795325112867f,  0.7071067811865476f,  0.3826834323650898f,
    0.f, -0.3826834323650898f, -0.7071067811865476f, -0.9238795325112867f,
   -1.f, -0.9238795325112867f, -0.7071067811865476f, -0.3826834323650898f,
    0.f,  0.3826834323650898f,  0.7071067811865476f,  0.9238795325112867f};
constexpr float S16T[16] = {
    0.f,  0.3826834323650898f,  0.7071067811865476f,  0.9238795325112867f,
    1.f,  0.9238795325112867f,  0.7071067811865476f,  0.3826834323650898f,
    0.f, -0.3826834323650898f, -0.7071067811865476f, -0.9238795325112867f,
   -1.f, -0.9238795325112867f, -0.7071067811865476f, -0.3826834323650898f};

__device__ __forceinline__ void dft16(const float* xr, const float* xi,
                                      float* Xr, float* Xi, const float sgn) {
  float Tr[4][4], Ti[4][4];
#pragma unroll
  for (int c0 = 0; c0 < 4; ++c0) {
    float ar = xr[c0],      ai = xi[c0];
    float br = xr[c0 + 4],  bi = xi[c0 + 4];
    float cr = xr[c0 + 8],  ci = xi[c0 + 8];
    float dr = xr[c0 + 12], di = xi[c0 + 12];
    float Er = ar + cr, Ei = ai + ci, Fr = ar - cr, Fi = ai - ci;
    float Gr = br + dr, Gi = bi + di, Hr = br - dr, Hi = bi - di;
    Tr[c0][0] = Er + Gr; Ti[c0][0] = Ei + Gi;
    Tr[c0][2] = Er - Gr; Ti[c0][2] = Ei - Gi;
    float wHr = -sgn * Hi, wHi = sgn * Hr;
    Tr[c0][1] = Fr + wHr; Ti[c0][1] = Fi + wHi;
    Tr[c0][3] = Fr - wHr; Ti[c0][3] = Fi - wHi;
  }
#pragma unroll
  for (int u = 0; u < 16; ++u) {
    const int m = u & 3;
    float sr = Tr[0][m], si = Ti[0][m];
#pragma unroll
    for (int c0 = 1; c0 < 4; ++c0) {
      const int k = (u * c0) & 15;
      const float wr = C16T[k];
      const float wi = sgn * S16T[k];
      sr += wr * Tr[c0][m] - wi * Ti[c0][m];
      si += wr * Ti[c0][m] + wi * Tr[c0][m];
    }
    Xr[u] = sr; Xi[u] = si;
  }
}

// ---------------- fold spectral filter into encoder weights -----------------
// Writes interleaved B'' [1536][768] bf16: for output-channel c,
//   re -> row (c>>5)*64 + (c&31),  im -> row (c>>5)*64 + 32 + (c&31).
__global__ __launch_bounds__(256) void fold_filter(
    const float* __restrict__ We, const float* __restrict__ be,
    const float* __restrict__ fre, const float* __restrict__ fim,
    unsigned short* __restrict__ Bpp, float* __restrict__ be_re,
    float* __restrict__ be_im) {
  __shared__ float2 S[16 * 276];
  const int tid = threadIdx.x;
  const int p = tid >> 4;
  const int q = tid & 15;
  const int item = blockIdx.x * 16 + p;
  const bool isW = item < 2304;
  const bool isB = (item >= 2304) && (item < 2307);
  const int e = isW ? (item / 3) : 0;
  const int ch = isW ? (item % 3) : (isB ? (item - 2304) : 0);
  const int sb = p * 276;

  {
    float xr[16], xi[16], Xr[16], Xi[16];
#pragma unroll
    for (int c = 0; c < 16; ++c) {
      const int crow = ch * 256 + q * 16 + c;
      xr[c] = isW ? We[(size_t)crow * 768 + e] : be[crow];
      xi[c] = 0.f;
    }
    dft16(xr, xi, Xr, Xi, -1.f);
#pragma unroll
    for (int u = 0; u < 16; ++u) S[sb + q * 17 + u] = make_float2(Xr[u], Xi[u]);
  }
  __syncthreads();

  {
    float xr[16], xi[16], Xr[16], Xi[16];
#pragma unroll
    for (int k = 0; k < 16; ++k) {
      float2 t = S[sb + k * 17 + q];
      xr[k] = t.x; xi[k] = t.y;
    }
    dft16(xr, xi, Xr, Xi, -1.f);
#pragma unroll
    for (int v = 0; v < 16; ++v) {
      float fr = fre[v * 16 + q], fi = fim[v * 16 + q];
      float tr = Xr[v] * fr - Xi[v] * fi;
      float ti = Xr[v] * fi + Xi[v] * fr;
      xr[v] = tr; xi[v] = ti;
    }
    dft16(xr, xi, Xr, Xi, 1.f);
#pragma unroll
    for (int r = 0; r < 16; ++r) S[sb + r * 17 + q] = make_float2(Xr[r], Xi[r]);
  }
  __syncthreads();

  {
    float xr[16], xi[16], Xr[16], Xi[16];
#pragma unroll
    for (int u = 0; u < 16; ++u) {
      float2 t = S[sb + q * 17 + u];
      xr[u] = t.x; xi[u] = t.y;
    }
    dft16(xr, xi, Xr, Xi, 1.f);
#pragma unroll
    for (int c = 0; c < 16; ++c) {
      const int crow = ch * 256 + q * 16 + c;
      const float rr = Xr[c] * (1.f / 256.f);
      const float ri = Xi[c] * (1.f / 256.f);
      if (isW) {
        const size_t rre = (size_t)(crow >> 5) * 64 + (crow & 31);
        Bpp[(rre)*768 + e]      = f32_to_bf16(rr);
        Bpp[(rre + 32)*768 + e] = f32_to_bf16(ri);
      } else if (isB) {
        be_re[crow] = rr;
        be_im[crow] = ri;
      }
    }
  }
}

// ---------------- 8-phase fine-interleaved MFMA GEMM -------------------------
// C = A[M,K] * B[NB,K]^T. Tile BM=128 x BN=256 B-rows, BK=64. 512 thr = 8
// waves (2 wm x 4 wn), per-wave 64x64, acc[4][4]. LDS 96 KB dbuf.
// Per K-tile: 4 phases x {ds_read subtile ; stage one 16KB chunk ; barrier ;
// lgkmcnt(0) ; setprio(1) ; 8 MFMA ; setprio(0) ; barrier}. Counted vmcnt(2)
// folded into ph3's closing barrier (never 0 mid-loop).
// Stage ledger: kt.ph0: B-h0(kt+1), ph1: B-h1(kt+1), ph3: A(kt+2).
// Write-after-read safety: A(kt) last read ph2-top (certified ph2 end-bar);
// B(kt-1) last read (kt-1).ph3-top (certified its end-bar, before kt.ph0).
template <int ENC>
__global__ __launch_bounds__(512, 2) void gemm_8p(
    const unsigned short* __restrict__ A, const unsigned short* __restrict__ B,
    const float* __restrict__ bias_re, const float* __restrict__ bias_im,
    void* __restrict__ out, int M, int K, int nbx) {
  __shared__ __align__(16) unsigned short As[2][128 * 64];
  __shared__ __align__(16) unsigned short Bs[2][256 * 64];

  const int tid = threadIdx.x;
  const int lane = tid & 63;
  const int wid = tid >> 6;        // 0..7
  const int wm = wid >> 2;         // 0..1  (64-row band)
  const int wn = wid & 3;          // 0..3  (64 B-row band)

  // bijective XCD swizzle (m204)
  const int nwg = gridDim.x;
  const int q8 = nwg >> 3, r8 = nwg & 7;
  const int xcd = blockIdx.x & 7, ii = blockIdx.x >> 3;
  const int lid = (xcd < r8 ? xcd * (q8 + 1) : r8 * (q8 + 1) + (xcd - r8) * q8) + ii;
  const int m0 = (lid / nbx) * 128;
  const int n0 = (lid % nbx) * 256;

  const int rA = (wid << 3) + (lane >> 3);   // staging row 0..63
  const int sl = (lane & 7) ^ (lane >> 3);   // pre-swizzled 16B slot

  char* AsC = (char*)&As[0][0];
  char* BsC = (char*)&Bs[0][0];

  // A K-tile = 128x64 = 16 KB = 1 chunk (2 loads/thread)
  auto STAGE_A = [&](int buf, int kt) {
    const unsigned short* g = A + (size_t)(m0 + rA) * K + (kt * 64 + sl * 8);
    gload_lds16(g, AsC + buf * 16384 + (wid << 10));
    gload_lds16(g + (size_t)64 * K, AsC + buf * 16384 + 8192 + (wid << 10));
  };
  // B K-tile = 256x64 = 32 KB = 2 chunks of 128 rows (2 loads/thread each)
  auto STAGE_B = [&](int buf, int kt, int h) {
    const unsigned short* g =
        B + (size_t)(n0 + h * 128 + rA) * K + (kt * 64 + sl * 8);
    gload_lds16(g, BsC + buf * 32768 + h * 16384 + (wid << 10));
    gload_lds16(g + (size_t)64 * K,
                BsC + buf * 32768 + h * 16384 + 8192 + (wid << 10));
  };

  const int rsel = lane & 15;
  const int swz = (lane & 7) << 4;
  const int kq = (lane >> 4) << 4;

  short8 af[4], bf0[2], bf1[2];
  f32x4 acc[4][4] = {};

  auto LD_A = [&](int buf, int kk) {
    const char* p = AsC + buf * 16384;
    const int kb = (kk * 64 + kq) ^ swz;
#pragma unroll
    for (int m = 0; m < 4; ++m)
      af[m] = *(const short8*)(p + (wm * 64 + m * 16 + rsel) * 128 + kb);
  };
  auto LD_B = [&](int buf, int kk, int np, short8* bf) {
    const char* p = BsC + buf * 32768;
    const int kb = (kk * 64 + kq) ^ swz;
#pragma unroll
    for (int j = 0; j < 2; ++j)
      bf[j] = *(const short8*)(p + (wn * 64 + (np * 2 + j) * 16 + rsel) * 128 + kb);
  };
  auto MFMA8 = [&](short8* bf, int np) {
    __builtin_amdgcn_s_setprio(1);
#pragma unroll
    for (int m = 0; m < 4; ++m)
#pragma unroll
      for (int j = 0; j < 2; ++j)
        acc[m][np * 2 + j] = __builtin_amdgcn_mfma_f32_16x16x32_bf16(
            af[m], bf[j], acc[m][np * 2 + j], 0, 0, 0);
    __builtin_amdgcn_s_setprio(0);
  };

#define BAR() asm volatile("s_barrier" ::: "memory")
#define LGKM0()                                         \
  do {                                                  \
    asm volatile("s_waitcnt lgkmcnt(0)" ::: "memory");  \
    __builtin_amdgcn_sched_barrier(0);                  \
  } while (0)

  const int nk = K >> 6;  // 12

  // prologue: A(0), B(0) both halves, A(1); need first 6 landed -> vmcnt(2)
  STAGE_A(0, 0);
  STAGE_B(0, 0, 0);
  STAGE_B(0, 0, 1);
  STAGE_A(1, 1);
  asm volatile("s_waitcnt vmcnt(2)" ::: "memory");
  BAR();

  for (int kt = 0; kt < nk; ++kt) {
    const int buf = kt & 1;
    const bool s1 = (kt + 1 < nk), s2 = (kt + 2 < nk);
    // ph0: af@kk0 + bf[0,1]@kk0 ; stage B-h0(kt+1)
    LD_A(buf, 0);
    LD_B(buf, 0, 0, bf0);
    if (s1) STAGE_B(buf ^ 1, kt + 1, 0);
    BAR(); LGKM0();
    MFMA8(bf0, 0);
    BAR();
    // ph1: bf[2,3]@kk0 ; stage B-h1(kt+1)
    LD_B(buf, 0, 1, bf1);
    if (s1) STAGE_B(buf ^ 1, kt + 1, 1);
    BAR(); LGKM0();
    MFMA8(bf1, 1);
    BAR();
    // ph2: af@kk1 + bf[0,1]@kk1 (A(kt) fully read after this phase)
    LD_A(buf, 1);
    LD_B(buf, 1, 0, bf0);
    BAR(); LGKM0();
    MFMA8(bf0, 0);
    BAR();
    // ph3: bf[2,3]@kk1 ; stage A(kt+2) into freed A region of this buf
    LD_B(buf, 1, 1, bf1);
    if (s2) STAGE_A(buf, kt + 2);
    BAR(); LGKM0();
    MFMA8(bf1, 1);
    if (s2)
      asm volatile("s_waitcnt vmcnt(2)" ::: "memory");  // A(kt+2) may fly
    else
      asm volatile("s_waitcnt vmcnt(0)" ::: "memory");
    BAR();  // publishes tile kt+1 to all waves
  }
#undef BAR
#undef LGKM0

  // C/D layout: col = lane&15, row = (lane>>4)*4 + j
  const int fr = lane & 15, fq = lane >> 4;
  if (ENC) {
    const int cbase = (n0 + wn * 64) >> 1;  // 64 B''-rows -> 32 output cols
    unsigned short* o = (unsigned short*)out;
#pragma unroll
    for (int n = 0; n < 2; ++n) {
      const int gcol = cbase + n * 16 + fr;
      const float br = bias_re[gcol], bi = bias_im[gcol];
#pragma unroll
      for (int m = 0; m < 4; ++m) {
        const int grow = m0 + wm * 64 + m * 16 + fq * 4;
#pragma unroll
        for (int j = 0; j < 4; ++j) {
          const float re = acc[m][n][j] + br;
          const float im = acc[m][n + 2][j] + bi;
          o[(size_t)(grow + j) * 768 + gcol] =
              f32_to_bf16(sqrtf(re * re + im * im));
        }
      }
    }
  } else {
    float* o = (float*)out;
#pragma unroll
    for (int n = 0; n < 4; ++n) {
      const int gcol = n0 + wn * 64 + n * 16 + fr;
      const float bv = bias_re[gcol];
#pragma unroll
      for (int m = 0; m < 4; ++m) {
        const int grow = m0 + wm * 64 + m * 16 + fq * 4;
#pragma unroll
        for (int j = 0; j < 4; ++j)
          o[(size_t)(grow + j) * 768 + gcol] = acc[m][n][j] + bv;
      }
    }
  }
}

// ---------------- launcher ---------------------------------------------------
extern "C" void kernel_launch(void* const* d_in, const int* in_sizes, int n_in,
                              void* d_out, int out_size, void* d_ws,
                              size_t ws_size, hipStream_t stream) {
  const float* x   = (const float*)d_in[0];
  const float* We  = (const float*)d_in[1];
  const float* be  = (const float*)d_in[2];
  const float* fre = (const float*)d_in[3];
  const float* fim = (const float*)d_in[4];
  const float* Wd  = (const float*)d_in[5];
  const float* bd  = (const float*)d_in[6];

  const int E = 768, C = 768;
  const int nX = in_sizes[0];                  // 19,267,584
  const int M  = nX / E;                       // 25088
  const int nW = E * C;                        // 589,824

  char* w = (char*)d_ws;
  unsigned short* xb    = (unsigned short*)w;                    // nX bf16
  unsigned short* Wdb   = (unsigned short*)(w + (size_t)nX * 2); // nW bf16
  unsigned short* Bpp   = Wdb + nW;                              // 2*nW bf16
  float*          be_re = (float*)(Bpp + 2 * (size_t)nW);
  float*          be_im = be_re + C;
  unsigned short* hb    = (unsigned short*)(be_im + C);          // nX bf16

  cvt_f32_bf16<<<(nX / 8 + 255) / 256, 256, 0, stream>>>(x, xb, nX / 8);
  cvt_f32_bf16<<<(nW / 8 + 255) / 256, 256, 0, stream>>>(Wd, Wdb, nW / 8);

  // fold ifft2(fft2(.)*filt)/256 into interleaved complex encoder weights
  fold_filter<<<145, 256, 0, stream>>>(We, be, fre, fim, Bpp, be_re, be_im);

  // a = |x @ We'^T + be'|  (bf16, in ws); grid 196*6 = 1176
  const int nbx1 = (2 * C) / 256;              // 6
  gemm_8p<1><<<nbx1 * (M / 128), 512, 0, stream>>>(xb, Bpp, be_re, be_im, hb,
                                                   M, E, nbx1);

  // out = a @ Wd^T + bd  (f32); grid 196*3 = 588
  const int nbx2 = E / 256;                    // 3
  gemm_8p<0><<<nbx2 * (M / 128), 512, 0, stream>>>(hb, Wdb, bd, nullptr,
                                                   (float*)d_out, M, C, nbx2);
}

// Round 7
// 163.853 us; speedup vs baseline: 1.0167x; 1.0167x over previous
//
#include <hip/hip_runtime.h>

typedef short short8 __attribute__((ext_vector_type(8)));
typedef unsigned short ushort8 __attribute__((ext_vector_type(8)));
typedef float f32x4 __attribute__((ext_vector_type(4)));

__device__ __forceinline__ unsigned short f32_to_bf16(float f) {
  unsigned u = __float_as_uint(f);
  unsigned r = 0x7fffu + ((u >> 16) & 1u);
  return (unsigned short)((u + r) >> 16);
}
__device__ __forceinline__ float bf16_to_f32(unsigned short h) {
  return __uint_as_float(((unsigned)h) << 16);
}

// ---------------- f32 -> bf16 convert (vectorized, 8 elems/thread) ----------
__global__ void cvt_f32_bf16(const float* __restrict__ s,
                             unsigned short* __restrict__ d, int n8) {
  int i = blockIdx.x * blockDim.x + threadIdx.x;
  if (i >= n8) return;
  const float4* sp = (const float4*)s;
  float4 a = sp[2 * i], b = sp[2 * i + 1];
  ushort8 o;
  o[0] = f32_to_bf16(a.x); o[1] = f32_to_bf16(a.y);
  o[2] = f32_to_bf16(a.z); o[3] = f32_to_bf16(a.w);
  o[4] = f32_to_bf16(b.x); o[5] = f32_to_bf16(b.y);
  o[6] = f32_to_bf16(b.z); o[7] = f32_to_bf16(b.w);
  ((ushort8*)d)[i] = o;
}

// ---------------- async global->LDS (16B/lane, wave-uniform LDS base) -------
__device__ __forceinline__ void gload_lds16(const void* g, void* l) {
  auto* gp = (const __attribute__((address_space(1))) uint32_t*)((uintptr_t)g);
  auto* lp = (__attribute__((address_space(3))) uint32_t*)(uint32_t)(uintptr_t)l;
  __builtin_amdgcn_global_load_lds(gp, lp, 16, 0, 0);
}

// ---------------- 16-point DFT (radix 4x4, constant twiddles) ---------------
constexpr float C16T[16] = {
    1.f,  0.9238795325112867f,  0.7071067811865476f,  0.3826834323650898f,
    0.f, -0.3826834323650898f, -0.7071067811865476f, -0.9238795325112867f,
   -1.f, -0.9238795325112867f, -0.7071067811865476f, -0.3826834323650898f,
    0.f,  0.3826834323650898f,  0.7071067811865476f,  0.9238795325112867f};
constexpr float S16T[16] = {
    0.f,  0.3826834323650898f,  0.7071067811865476f,  0.9238795325112867f,
    1.f,  0.9238795325112867f,  0.7071067811865476f,  0.3826834323650898f,
    0.f, -0.3826834323650898f, -0.7071067811865476f, -0.9238795325112867f,
   -1.f, -0.9238795325112867f, -0.7071067811865476f, -0.3826834323650898f};

__device__ __forceinline__ void dft16(const float* xr, const float* xi,
                                      float* Xr, float* Xi, const float sgn) {
  float Tr[4][4], Ti[4][4];
#pragma unroll
  for (int c0 = 0; c0 < 4; ++c0) {
    float ar = xr[c0],      ai = xi[c0];
    float br = xr[c0 + 4],  bi = xi[c0 + 4];
    float cr = xr[c0 + 8],  ci = xi[c0 + 8];
    float dr = xr[c0 + 12], di = xi[c0 + 12];
    float Er = ar + cr, Ei = ai + ci, Fr = ar - cr, Fi = ai - ci;
    float Gr = br + dr, Gi = bi + di, Hr = br - dr, Hi = bi - di;
    Tr[c0][0] = Er + Gr; Ti[c0][0] = Ei + Gi;
    Tr[c0][2] = Er - Gr; Ti[c0][2] = Ei - Gi;
    float wHr = -sgn * Hi, wHi = sgn * Hr;
    Tr[c0][1] = Fr + wHr; Ti[c0][1] = Fi + wHi;
    Tr[c0][3] = Fr - wHr; Ti[c0][3] = Fi - wHi;
  }
#pragma unroll
  for (int u = 0; u < 16; ++u) {
    const int m = u & 3;
    float sr = Tr[0][m], si = Ti[0][m];
#pragma unroll
    for (int c0 = 1; c0 < 4; ++c0) {
      const int k = (u * c0) & 15;
      const float wr = C16T[k];
      const float wi = sgn * S16T[k];
      sr += wr * Tr[c0][m] - wi * Ti[c0][m];
      si += wr * Ti[c0][m] + wi * Tr[c0][m];
    }
    Xr[u] = sr; Xi[u] = si;
  }
}

// ---------------- fold spectral filter into encoder weights -----------------
// Writes interleaved B'' [1536][768] bf16: for output-channel c,
//   re -> row (c>>5)*64 + (c&31),  im -> row (c>>5)*64 + 32 + (c&31).
__global__ __launch_bounds__(256) void fold_filter(
    const float* __restrict__ We, const float* __restrict__ be,
    const float* __restrict__ fre, const float* __restrict__ fim,
    unsigned short* __restrict__ Bpp, float* __restrict__ be_re,
    float* __restrict__ be_im) {
  __shared__ float2 S[16 * 276];
  const int tid = threadIdx.x;
  const int p = tid >> 4;
  const int q = tid & 15;
  const int item = blockIdx.x * 16 + p;
  const bool isW = item < 2304;
  const bool isB = (item >= 2304) && (item < 2307);
  const int e = isW ? (item / 3) : 0;
  const int ch = isW ? (item % 3) : (isB ? (item - 2304) : 0);
  const int sb = p * 276;

  {
    float xr[16], xi[16], Xr[16], Xi[16];
#pragma unroll
    for (int c = 0; c < 16; ++c) {
      const int crow = ch * 256 + q * 16 + c;
      xr[c] = isW ? We[(size_t)crow * 768 + e] : be[crow];
      xi[c] = 0.f;
    }
    dft16(xr, xi, Xr, Xi, -1.f);
#pragma unroll
    for (int u = 0; u < 16; ++u) S[sb + q * 17 + u] = make_float2(Xr[u], Xi[u]);
  }
  __syncthreads();

  {
    float xr[16], xi[16], Xr[16], Xi[16];
#pragma unroll
    for (int k = 0; k < 16; ++k) {
      float2 t = S[sb + k * 17 + q];
      xr[k] = t.x; xi[k] = t.y;
    }
    dft16(xr, xi, Xr, Xi, -1.f);
#pragma unroll
    for (int v = 0; v < 16; ++v) {
      float fr = fre[v * 16 + q], fi = fim[v * 16 + q];
      float tr = Xr[v] * fr - Xi[v] * fi;
      float ti = Xr[v] * fi + Xi[v] * fr;
      xr[v] = tr; xi[v] = ti;
    }
    dft16(xr, xi, Xr, Xi, 1.f);
#pragma unroll
    for (int r = 0; r < 16; ++r) S[sb + r * 17 + q] = make_float2(Xr[r], Xi[r]);
  }
  __syncthreads();

  {
    float xr[16], xi[16], Xr[16], Xi[16];
#pragma unroll
    for (int u = 0; u < 16; ++u) {
      float2 t = S[sb + q * 17 + u];
      xr[u] = t.x; xi[u] = t.y;
    }
    dft16(xr, xi, Xr, Xi, 1.f);
#pragma unroll
    for (int c = 0; c < 16; ++c) {
      const int crow = ch * 256 + q * 16 + c;
      const float rr = Xr[c] * (1.f / 256.f);
      const float ri = Xi[c] * (1.f / 256.f);
      if (isW) {
        const size_t rre = (size_t)(crow >> 5) * 64 + (crow & 31);
        Bpp[(rre)*768 + e]      = f32_to_bf16(rr);
        Bpp[(rre + 32)*768 + e] = f32_to_bf16(ri);
      } else if (isB) {
        be_re[crow] = rr;
        be_im[crow] = ri;
      }
    }
  }
}

// ---------------- encode GEMM: R4 2-phase structure, N-MAJOR grid -----------
// A [M,768] bf16, B'' [1536,768] bf16 (interleaved re/im). 128x128 tile,
// BK=64, 4 waves, 2-phase prefetch, dbuf LDS, XOR-swizzle, XCD chunking.
// N-MAJOR lid order: consecutive lids share one 192 KB B-tile (XCD-L2 hot);
// B'' (4.7 MB) never needs to be L2-resident at once. A-panels stream (L3).
__global__ __launch_bounds__(256) void gemm_enc(
    const unsigned short* __restrict__ A, const unsigned short* __restrict__ B,
    const float* __restrict__ be_re, const float* __restrict__ be_im,
    unsigned short* __restrict__ out, int M, int K, int nmt) {
  __shared__ __align__(16) unsigned short As[2][128 * 64];
  __shared__ __align__(16) unsigned short Bs[2][128 * 64];

  const int tid = threadIdx.x;
  const int lane = tid & 63;
  const int wid = tid >> 6;
  const int wr = wid >> 1, wc = wid & 1;

  const int nwg = gridDim.x;
  const int cpx = nwg >> 3;
  const int bid = blockIdx.x;
  const int lid = (bid & 7) * cpx + (bid >> 3);
  // n-major: consecutive lid -> same n-tile (B-tile stays hot in XCD L2)
  const int m0 = (lid % nmt) * 128, n0 = (lid / nmt) * 128;

  const int lr8 = lane >> 3;
  const int swk = ((lane & 7) ^ lr8) * 8;

  f32x4 acc[4][4] = {};

  auto STAGE = [&](int buf, int k0) {
#pragma unroll
    for (int c = 0; c < 4; ++c) {
      const int rowc = wid * 32 + c * 8;
      gload_lds16(A + (size_t)(m0 + rowc + lr8) * K + (k0 + swk),
                  &As[buf][rowc * 64]);
      gload_lds16(B + (size_t)(n0 + rowc + lr8) * K + (k0 + swk),
                  &Bs[buf][rowc * 64]);
    }
  };

  const int rsel = lane & 15;
  auto COMPUTE = [&](int buf) {
#pragma unroll
    for (int ks = 0; ks < 2; ++ks) {
      const int kbyte = ks * 64 + (lane >> 4) * 16;
      short8 af[4], bf[4];
#pragma unroll
      for (int m = 0; m < 4; ++m) {
        const int row = wr * 64 + m * 16 + rsel;
        af[m] = *(const short8*)((const char*)&As[buf][0] +
                                 row * 128 + (kbyte ^ ((row & 7) << 4)));
      }
#pragma unroll
      for (int n = 0; n < 4; ++n) {
        const int row = wc * 64 + n * 16 + rsel;
        bf[n] = *(const short8*)((const char*)&Bs[buf][0] +
                                 row * 128 + (kbyte ^ ((row & 7) << 4)));
      }
#pragma unroll
      for (int m = 0; m < 4; ++m)
#pragma unroll
        for (int n = 0; n < 4; ++n)
          acc[m][n] = __builtin_amdgcn_mfma_f32_16x16x32_bf16(
              af[m], bf[n], acc[m][n], 0, 0, 0);
    }
  };

  const int nk = K >> 6;
  STAGE(0, 0);
  __syncthreads();
  int cur = 0;
  for (int t = 1; t < nk; ++t) {
    STAGE(cur ^ 1, t * 64);
    COMPUTE(cur);
    __syncthreads();
    cur ^= 1;
  }
  COMPUTE(cur);

  // acc[m][n] (n=0,1) = re, acc[m][n+2] = im of the same output column.
  const int fr = lane & 15, fq = lane >> 4;
  const int cbase = (n0 + wc * 64) >> 1;  // 64 B''-rows -> 32 output cols
#pragma unroll
  for (int n = 0; n < 2; ++n) {
    const int gcol = cbase + n * 16 + fr;
    const float br = be_re[gcol], bi = be_im[gcol];
#pragma unroll
    for (int m = 0; m < 4; ++m) {
      const int grow = m0 + wr * 64 + m * 16 + fq * 4;
#pragma unroll
      for (int j = 0; j < 4; ++j) {
        const float re = acc[m][n][j] + br;
        const float im = acc[m][n + 2][j] + bi;
        out[(size_t)(grow + j) * 768 + gcol] =
            f32_to_bf16(sqrtf(re * re + im * im));
      }
    }
  }
}

// ---------------- decode GEMM: C = A * B^T + bias, f32 out (m-major) --------
__global__ __launch_bounds__(256) void gemm_bt(
    const unsigned short* __restrict__ A, const unsigned short* __restrict__ B,
    const float* __restrict__ bias, float* __restrict__ out,
    int M, int N, int K, int nbx) {
  __shared__ __align__(16) unsigned short As[2][128 * 64];
  __shared__ __align__(16) unsigned short Bs[2][128 * 64];

  const int tid = threadIdx.x;
  const int lane = tid & 63;
  const int wid = tid >> 6;
  const int wr = wid >> 1, wc = wid & 1;

  const int nwg = gridDim.x;
  const int cpx = nwg >> 3;
  const int bid = blockIdx.x;
  const int lid = (bid & 7) * cpx + (bid >> 3);
  const int m0 = (lid / nbx) * 128, n0 = (lid % nbx) * 128;

  const int lr8 = lane >> 3;
  const int swk = ((lane & 7) ^ lr8) * 8;

  f32x4 acc[4][4] = {};

  auto STAGE = [&](int buf, int k0) {
#pragma unroll
    for (int c = 0; c < 4; ++c) {
      const int rowc = wid * 32 + c * 8;
      gload_lds16(A + (size_t)(m0 + rowc + lr8) * K + (k0 + swk),
                  &As[buf][rowc * 64]);
      gload_lds16(B + (size_t)(n0 + rowc + lr8) * K + (k0 + swk),
                  &Bs[buf][rowc * 64]);
    }
  };

  const int rsel = lane & 15;
  auto COMPUTE = [&](int buf) {
#pragma unroll
    for (int ks = 0; ks < 2; ++ks) {
      const int kbyte = ks * 64 + (lane >> 4) * 16;
      short8 af[4], bf[4];
#pragma unroll
      for (int m = 0; m < 4; ++m) {
        const int row = wr * 64 + m * 16 + rsel;
        af[m] = *(const short8*)((const char*)&As[buf][0] +
                                 row * 128 + (kbyte ^ ((row & 7) << 4)));
      }
#pragma unroll
      for (int n = 0; n < 4; ++n) {
        const int row = wc * 64 + n * 16 + rsel;
        bf[n] = *(const short8*)((const char*)&Bs[buf][0] +
                                 row * 128 + (kbyte ^ ((row & 7) << 4)));
      }
#pragma unroll
      for (int m = 0; m < 4; ++m)
#pragma unroll
        for (int n = 0; n < 4; ++n)
          acc[m][n] = __builtin_amdgcn_mfma_f32_16x16x32_bf16(
              af[m], bf[n], acc[m][n], 0, 0, 0);
    }
  };

  const int nk = K >> 6;
  STAGE(0, 0);
  __syncthreads();
  int cur = 0;
  for (int t = 1; t < nk; ++t) {
    STAGE(cur ^ 1, t * 64);
    COMPUTE(cur);
    __syncthreads();
    cur ^= 1;
  }
  COMPUTE(cur);

  const int fr = lane & 15, fq = lane >> 4;
#pragma unroll
  for (int n = 0; n < 4; ++n) {
    const int gcol = n0 + wc * 64 + n * 16 + fr;
    const float bv = bias[gcol];
#pragma unroll
    for (int m = 0; m < 4; ++m) {
      const int grow = m0 + wr * 64 + m * 16 + fq * 4;
#pragma unroll
      for (int j = 0; j < 4; ++j)
        out[(size_t)(grow + j) * N + gcol] = acc[m][n][j] + bv;
    }
  }
}

// ---------------- launcher ---------------------------------------------------
extern "C" void kernel_launch(void* const* d_in, const int* in_sizes, int n_in,
                              void* d_out, int out_size, void* d_ws,
                              size_t ws_size, hipStream_t stream) {
  const float* x   = (const float*)d_in[0];
  const float* We  = (const float*)d_in[1];
  const float* be  = (const float*)d_in[2];
  const float* fre = (const float*)d_in[3];
  const float* fim = (const float*)d_in[4];
  const float* Wd  = (const float*)d_in[5];
  const float* bd  = (const float*)d_in[6];

  const int E = 768, C = 768;
  const int nX = in_sizes[0];                  // 19,267,584
  const int M  = nX / E;                       // 25088
  const int nW = E * C;                        // 589,824

  char* w = (char*)d_ws;
  unsigned short* xb    = (unsigned short*)w;                    // nX bf16
  unsigned short* Wdb   = (unsigned short*)(w + (size_t)nX * 2); // nW bf16
  unsigned short* Bpp   = Wdb + nW;                              // 2*nW bf16
  float*          be_re = (float*)(Bpp + 2 * (size_t)nW);
  float*          be_im = be_re + C;
  unsigned short* hb    = (unsigned short*)(be_im + C);          // nX bf16

  cvt_f32_bf16<<<(nX / 8 + 255) / 256, 256, 0, stream>>>(x, xb, nX / 8);
  cvt_f32_bf16<<<(nW / 8 + 255) / 256, 256, 0, stream>>>(Wd, Wdb, nW / 8);

  // fold ifft2(fft2(.)*filt)/256 into interleaved complex encoder weights
  fold_filter<<<145, 256, 0, stream>>>(We, be, fre, fim, Bpp, be_re, be_im);

  // a = |x @ We'^T + be'|  (bf16, in ws); grid 2352 = 8*294, n-major
  const int nmt = M / 128;                     // 196
  gemm_enc<<<((2 * C) / 128) * nmt, 256, 0, stream>>>(xb, Bpp, be_re, be_im,
                                                      hb, M, E, nmt);

  // out = a @ Wd^T + bd  (f32); grid 1176 = 196*6, m-major
  const int nbx2 = E / 128;
  gemm_bt<<<nbx2 * (M / 128), 256, 0, stream>>>(hb, Wdb, bd, (float*)d_out, M,
                                                E, C, nbx2);
}